// Round 8
// baseline (645.833 us; speedup 1.0000x reference)
//
#include <hip/hip_runtime.h>
#include <math.h>
#include <float.h>

// Problem constants
#define N_SEQ 2048
#define DIMN  1024
#define NH    16
#define DH    64
#define ROT   32
#define MEM   16
#define JTOT  (N_SEQ + MEM)   // 2064
#define JP    2112            // padded to x32 (pad keys zeroed, masked)
#define NB    32
#define REL_SCALE 8.0f
#define C_SPLIT 11
#define JSP   192             // 6 tiles of 32; 11*192 = 2112 = JP
#define JPLANE 257            // LDS plane stride for S

typedef __attribute__((ext_vector_type(8))) _Float16 half8;
typedef __attribute__((ext_vector_type(4))) _Float16 half4;
typedef __attribute__((ext_vector_type(4))) float floatx4;

// ---------------------------------------------------------------------------
// f32 -> f16 elementwise (vectorized)
// ---------------------------------------------------------------------------
__global__ __launch_bounds__(256) void convert_f16(
    const float* __restrict__ in, _Float16* __restrict__ out, int n4)
{
  const int t = blockIdx.x * 256 + threadIdx.x;
  if (t >= n4) return;
  float4 v = ((const float4*)in)[t];
  half4 o = { (_Float16)v.x, (_Float16)v.y, (_Float16)v.z, (_Float16)v.w };
  *(half4*)&out[(size_t)t * 4] = o;
}

// ---------------------------------------------------------------------------
// W [K][N] f32 -> WT [N][K] f16 (64x64 LDS tiles)
// ---------------------------------------------------------------------------
__global__ __launch_bounds__(256) void convtrans(
    const float* __restrict__ W, _Float16* __restrict__ WT, int K, int N)
{
  __shared__ _Float16 tile[64][72];
  const int k0 = blockIdx.y * 64, n0 = blockIdx.x * 64;
  const int t = threadIdx.x;
#pragma unroll
  for (int p = 0; p < 4; ++p) {
    const int r = (t >> 4) + 16 * p;
    const int c = (t & 15) * 4;
    float4 wv = *(const float4*)&W[(size_t)(k0 + r) * N + n0 + c];
    tile[r][c + 0] = (_Float16)wv.x;
    tile[r][c + 1] = (_Float16)wv.y;
    tile[r][c + 2] = (_Float16)wv.z;
    tile[r][c + 3] = (_Float16)wv.w;
  }
  __syncthreads();
#pragma unroll
  for (int p = 0; p < 2; ++p) {
    const int n = (t >> 3) + 32 * p;
    const int kc = (t & 7) * 8;
    half8 o;
#pragma unroll
    for (int j = 0; j < 8; ++j) o[j] = tile[kc + j][n];
    *(half8*)&WT[(size_t)(n0 + n) * K + k0 + kc] = o;
  }
}

// ---------------------------------------------------------------------------
// fp16 MFMA GEMM: C(f32) = A(f16,[M][K]) @ BT(f16,[N][K])^T (+bias)
// ---------------------------------------------------------------------------
__global__ __launch_bounds__(256) void gemm_f16(
    const _Float16* __restrict__ A, const _Float16* __restrict__ BT,
    float* __restrict__ C, const float* __restrict__ bias,
    int M, int K, int N)
{
  const int tid = threadIdx.x;
  const int w = tid >> 6, lane = tid & 63;
  const int m0 = blockIdx.y * 64 + w * 16;
  const int n0 = blockIdx.x * 64;
  const int lr = lane & 15, lk = (lane >> 4) * 8;
  const _Float16* Ap = A + (size_t)(m0 + lr) * K + lk;
  const _Float16* Bp = BT + (size_t)(n0 + lr) * K + lk;
  floatx4 acc[4];
#pragma unroll
  for (int T = 0; T < 4; ++T) acc[T] = (floatx4){0.f, 0.f, 0.f, 0.f};
#pragma unroll 2
  for (int k0 = 0; k0 < K; k0 += 32) {
    half8 af = *(const half8*)(Ap + k0);
#pragma unroll
    for (int T = 0; T < 4; ++T) {
      half8 bf = *(const half8*)(Bp + (size_t)T * 16 * K + k0);
      acc[T] = __builtin_amdgcn_mfma_f32_16x16x32_f16(af, bf, acc[T], 0, 0, 0);
    }
  }
#pragma unroll
  for (int T = 0; T < 4; ++T) {
    const int col = n0 + T * 16 + lr;
    const float bb = bias ? bias[col] : 0.f;
#pragma unroll
    for (int r = 0; r < 4; ++r) {
      const int row = m0 + (lane >> 4) * 4 + r;
      C[(size_t)row * N + col] = acc[T][r] + bb;
    }
  }
}

// ---------------------------------------------------------------------------
// Rotary + l2norm + fp16 layout. qh scaled by 1/clip(exp(qk_scale),0.01).
// ---------------------------------------------------------------------------
__global__ __launch_bounds__(256) void postproc(
    const float* __restrict__ tmp, const float* __restrict__ rot,
    const float* __restrict__ mem_k, const float* __restrict__ mem_v,
    const float* __restrict__ qk_scale,
    _Float16* __restrict__ qh, _Float16* __restrict__ kh, _Float16* __restrict__ vh)
{
  const int gw = (blockIdx.x * 256 + threadIdx.x) >> 6;
  const int lane = threadIdx.x & 63;
  const int TQ = NH * N_SEQ;
  const int TM = TQ + NH * MEM;
  const int TP = TM + NH * (JP - JTOT);
  if (gw < TQ) {
    const int h = gw >> 11;
    const int i = gw & (N_SEQ - 1);
    const size_t base = (size_t)i * DIMN + h * DH + lane;
    float q = tmp[base];
    float k = tmp[base + (size_t)N_SEQ * DIMN];
    float v = tmp[base + 2 * (size_t)N_SEQ * DIMN];
    float cf = 1.f, sf = 0.f;
    if (lane < ROT) { float f = rot[(size_t)i * ROT + lane]; cf = cosf(f); sf = sinf(f); }
    float qp = __shfl_xor(q, 16);
    float kp = __shfl_xor(k, 16);
    float vp = __shfl_xor(v, 16);
    if (lane < ROT) {
      float sgn = (lane < 16) ? -1.f : 1.f;
      q = q * cf + sgn * qp * sf;
      k = k * cf + sgn * kp * sf;
      v = v * cf + sgn * vp * sf;
    }
    float nq = q * q, nk = k * k;
#pragma unroll
    for (int off = 32; off; off >>= 1) { nq += __shfl_xor(nq, off); nk += __shfl_xor(nk, off); }
    q *= 1.f / fmaxf(sqrtf(nq), 1e-12f);
    k *= 1.f / fmaxf(sqrtf(nk), 1e-12f);
    float scl = 1.0f / fmaxf(__expf(qk_scale[h]), 0.01f);
    qh[((size_t)h * N_SEQ + i) * DH + lane] = (_Float16)(q * scl);
    kh[((size_t)h * JP + MEM + i) * DH + lane] = (_Float16)k;
    vh[((size_t)h * JP + MEM + i) * DH + lane] = (_Float16)v;
  } else if (gw < TM) {
    const int r = gw - TQ;
    const int h = r >> 4, mm = r & 15;
    float k = mem_k[((size_t)h * MEM + mm) * DH + lane];
    float v = mem_v[((size_t)h * MEM + mm) * DH + lane];
    float nk = k * k;
#pragma unroll
    for (int off = 32; off; off >>= 1) nk += __shfl_xor(nk, off);
    k *= 1.f / fmaxf(sqrtf(nk), 1e-12f);
    kh[((size_t)h * JP + mm) * DH + lane] = (_Float16)k;
    vh[((size_t)h * JP + mm) * DH + lane] = (_Float16)v;
  } else if (gw < TP) {
    const int r = gw - TM;
    const int h = r / (JP - JTOT), jr = JTOT + r % (JP - JTOT);
    kh[((size_t)h * JP + jr) * DH + lane] = (_Float16)0.f;
    vh[((size_t)h * JP + jr) * DH + lane] = (_Float16)0.f;
  }
}

// ---------------------------------------------------------------------------
// vh[h][j][d] -> vT[h][d][j]
// ---------------------------------------------------------------------------
__global__ __launch_bounds__(256) void transpose_v(
    const _Float16* __restrict__ vh, _Float16* __restrict__ vT)
{
  __shared__ _Float16 tile[64][72];
  const int h = blockIdx.y;
  const int j0 = blockIdx.x * 64;
  const int t = threadIdx.x;
#pragma unroll
  for (int p = 0; p < 2; ++p) {
    const int jr = (t >> 3) + 32 * p;
    const int dc = (t & 7) * 8;
    half8 v = *(const half8*)(vh + ((size_t)h * JP + j0 + jr) * DH + dc);
    *(half8*)&tile[jr][dc] = v;
  }
  __syncthreads();
#pragma unroll
  for (int p = 0; p < 2; ++p) {
    const int d = (t >> 3) + 32 * p;
    const int jc = (t & 7) * 8;
    half8 o;
#pragma unroll
    for (int r = 0; r < 8; ++r) o[r] = tile[jc + r][d];
    *(half8*)(vT + ((size_t)h * DH + d) * JP + j0 + jc) = o;
  }
}

__device__ __forceinline__ int rel_bucket(int n) {
  if (n < 0) n = 0;
  if (n < 16) return n;
  int v = 16 + (int)(logf((float)n * 0.0625f) * 7.6944042f);
  return v > 31 ? 31 : v;
}

// ---------------------------------------------------------------------------
// Pass 1 (512 thr, 8 waves x 2 heads): QK MFMA -> premix -> per-thread
// online (m,l) (1 j-col/thread) -> shfl merge -> mpart.
// __launch_bounds__(512,2): 256-VGPR cap ((512,4) spilled m/l -> R6).
// C_SPLIT=11: longest block 6 tiles (was 11) -> shorter critical path,
// 758 active blocks (~3/CU) for cross-block latency overlap.
// ---------------------------------------------------------------------------
__global__ __launch_bounds__(512, 2) void attn_pass1(
    const _Float16* __restrict__ qh, const _Float16* __restrict__ kh,
    const float* __restrict__ pre_proj, const float* __restrict__ rel_table,
    float* __restrict__ mpart, float* __restrict__ lpart)
{
  const int i0 = blockIdx.x * 16;
  const int c = blockIdx.y;
  const int jlo = c * JSP;
  if (jlo >= i0 + 32) return;
  const int jhi = min(min(jlo + JSP, JP), (i0 + 63) & ~31);
  const int tid = threadIdx.x;
  const int lane = tid & 63, w = tid >> 6;

  __shared__ float S_lds[32 * JPLANE];   // 32,896 B
  __shared__ float pre_s[256];
  __shared__ float relt[NB * NH];        // 512

  if (tid < 256) pre_s[tid] = pre_proj[tid];
  relt[tid] = rel_table[tid] * REL_SCALE;

  half8 qf[2][2];
#pragma unroll
  for (int n = 0; n < 2; ++n) {
    const int h = w * 2 + n;
    const _Float16* qb = qh + ((size_t)h * N_SEQ + i0 + (lane & 15)) * DH + (lane >> 4) * 8;
    qf[n][0] = *(const half8*)qb;
    qf[n][1] = *(const half8*)(qb + 32);
  }
  float m[16], l[16];
#pragma unroll
  for (int k = 0; k < 16; ++k) { m[k] = -1e30f; l[k] = 0.f; }
  const int ti = tid >> 5;       // query row 0..15
  const int tj = tid & 31;       // j column within tile
  const int ig = i0 + ti;
  __syncthreads();

  for (int jb = jlo; jb < jhi; jb += 32) {
    // ---- QK MFMA -> S_lds (fp32) ----
#pragma unroll
    for (int n = 0; n < 2; ++n) {
      const int h = w * 2 + n;
#pragma unroll
      for (int T = 0; T < 2; ++T) {
        floatx4 acc = {0.f, 0.f, 0.f, 0.f};
        const _Float16* kb = kh + ((size_t)h * JP + jb + 16 * T + (lane & 15)) * DH + (lane >> 4) * 8;
        acc = __builtin_amdgcn_mfma_f32_16x16x32_f16(qf[n][0], *(const half8*)kb, acc, 0, 0, 0);
        acc = __builtin_amdgcn_mfma_f32_16x16x32_f16(qf[n][1], *(const half8*)(kb + 32), acc, 0, 0, 0);
        const int jcol = (lane & 15) + 16 * T;
        const int row0 = (lane >> 4) * 4;
#pragma unroll
        for (int r = 0; r < 4; ++r) S_lds[jcol * JPLANE + h * 16 + row0 + r] = acc[r];
      }
    }
    __syncthreads();
    // ---- premix + online (m,l), one column per thread ----
    const int jg = jb + tj;
    const bool valid = (jg <= ig + MEM) && (jg < JTOT);
    if (valid) {
      const int rb = rel_bucket(ig - jg) * 16;
#pragma unroll
      for (int kc = 0; kc < 2; ++kc) {
        float sa[8];
#pragma unroll
        for (int q = 0; q < 8; ++q) sa[q] = 0.f;
#pragma unroll
        for (int h = 0; h < 16; ++h) {
          float s = S_lds[tj * JPLANE + h * 16 + ti];
          float4 pa = *(const float4*)&pre_s[h * 16 + kc * 8];
          float4 pb = *(const float4*)&pre_s[h * 16 + kc * 8 + 4];
          sa[0] += s * pa.x; sa[1] += s * pa.y; sa[2] += s * pa.z; sa[3] += s * pa.w;
          sa[4] += s * pb.x; sa[5] += s * pb.y; sa[6] += s * pb.z; sa[7] += s * pb.w;
        }
#pragma unroll
        for (int kk = 0; kk < 8; ++kk) {
          const int k = kc * 8 + kk;
          const float s = sa[kk] + relt[rb + k];
          const float mo = m[k];
          const float mn = fmaxf(mo, s);
          const float e = __expf(fminf(mo, s) - mn);
          l[k] = (s > mo) ? (l[k] * e + 1.0f) : (l[k] + e);
          m[k] = mn;
        }
      }
    }
    __syncthreads();
  }
  // ---- shfl-butterfly (m,l) merge over the 32 j-threads of each row ----
#pragma unroll
  for (int off = 1; off < 32; off <<= 1) {
#pragma unroll
    for (int k = 0; k < 16; ++k) {
      float mo = __shfl_xor(m[k], off);
      float lo = __shfl_xor(l[k], off);
      float mn = fmaxf(m[k], mo);
      l[k] = l[k] * __expf(m[k] - mn) + lo * __expf(mo - mn);
      m[k] = mn;
    }
  }
  if (tj == 0) {
#pragma unroll
    for (int k = 0; k < 16; ++k) {
      mpart[((size_t)c * NH + k) * N_SEQ + ig] = m[k];
      lpart[((size_t)c * NH + k) * N_SEQ + ig] = l[k];
    }
  }
}

// ---------------------------------------------------------------------------
__global__ __launch_bounds__(256) void merge_ml(
    const float* __restrict__ mpart, const float* __restrict__ lpart,
    float* __restrict__ Mf, float* __restrict__ Lf)
{
  const int t = blockIdx.x * 256 + threadIdx.x;
  const int i = t & (N_SEQ - 1);
  const int lim = (i & ~15) + 32;
  const int h = t >> 11;
  float m = -1e30f;
#pragma unroll
  for (int c = 0; c < C_SPLIT; ++c)
    if (c * JSP < lim) m = fmaxf(m, mpart[((size_t)c * NH + h) * N_SEQ + i]);
  float l = 0.f;
#pragma unroll
  for (int c = 0; c < C_SPLIT; ++c)
    if (c * JSP < lim) {
      float mc = mpart[((size_t)c * NH + h) * N_SEQ + i];
      l += lpart[((size_t)c * NH + h) * N_SEQ + i] * __expf(mc - m);
    }
  Mf[t] = m;
  Lf[t] = l;
}

// ---------------------------------------------------------------------------
// Pass 2 (512 thr, 8 waves x 2 heads): QK MFMA -> premix -> p -> fused
// register postmix (1 j-col/thread) -> P_lds f16 -> PV MFMA -> atomic ctx.
// ---------------------------------------------------------------------------
__global__ __launch_bounds__(512, 2) void attn_pass2(
    const _Float16* __restrict__ qh, const _Float16* __restrict__ kh,
    const _Float16* __restrict__ vT,
    const float* __restrict__ pre_proj, const float* __restrict__ post_proj,
    const float* __restrict__ rel_table,
    const float* __restrict__ Mf, const float* __restrict__ Lf,
    float* __restrict__ ctx)
{
  const int i0 = blockIdx.x * 16;
  const int c = blockIdx.y;
  const int jlo = c * JSP;
  if (jlo >= i0 + 32) return;
  const int jhi = min(min(jlo + JSP, JP), (i0 + 63) & ~31);
  const int tid = threadIdx.x;
  const int lane = tid & 63, w = tid >> 6;

  __shared__ float S_lds[32 * JPLANE];      // 32,896 B
  __shared__ _Float16 P_lds[256 * 40];      // 20,480 B
  __shared__ float pre_s[256], post_s[256];
  __shared__ float relt[NB * NH];           // 512
  __shared__ float Ml[256], iLl[256];

  if (tid < 256) {
    pre_s[tid] = pre_proj[tid];
    post_s[tid] = post_proj[tid];
    const int k = tid >> 4, i2 = tid & 15;
    Ml[tid] = Mf[(size_t)k * N_SEQ + i0 + i2];
    iLl[tid] = 1.0f / Lf[(size_t)k * N_SEQ + i0 + i2];
  }
  relt[tid] = rel_table[tid] * REL_SCALE;

  half8 qf[2][2];
#pragma unroll
  for (int n = 0; n < 2; ++n) {
    const int h = w * 2 + n;
    const _Float16* qb = qh + ((size_t)h * N_SEQ + i0 + (lane & 15)) * DH + (lane >> 4) * 8;
    qf[n][0] = *(const half8*)qb;
    qf[n][1] = *(const half8*)(qb + 32);
  }
  const int ti = tid >> 5;       // query row 0..15
  const int tj = tid & 31;       // j column within tile
  const int ig = i0 + ti;
  floatx4 oacc[2][4];
#pragma unroll
  for (int n = 0; n < 2; ++n)
#pragma unroll
    for (int T = 0; T < 4; ++T) oacc[n][T] = (floatx4){0.f, 0.f, 0.f, 0.f};
  __syncthreads();

  for (int jb = jlo; jb < jhi; jb += 32) {
    // ---- QK MFMA -> S_lds (fp32) ----
#pragma unroll
    for (int n = 0; n < 2; ++n) {
      const int h = w * 2 + n;
#pragma unroll
      for (int T = 0; T < 2; ++T) {
        floatx4 acc = {0.f, 0.f, 0.f, 0.f};
        const _Float16* kb = kh + ((size_t)h * JP + jb + 16 * T + (lane & 15)) * DH + (lane >> 4) * 8;
        acc = __builtin_amdgcn_mfma_f32_16x16x32_f16(qf[n][0], *(const half8*)kb, acc, 0, 0, 0);
        acc = __builtin_amdgcn_mfma_f32_16x16x32_f16(qf[n][1], *(const half8*)(kb + 32), acc, 0, 0, 0);
        const int jcol = (lane & 15) + 16 * T;
        const int row0 = (lane >> 4) * 4;
#pragma unroll
        for (int r = 0; r < 4; ++r) S_lds[jcol * JPLANE + h * 16 + row0 + r] = acc[r];
      }
    }
    __syncthreads();
    // ---- premix -> p -> fused postmix (one column per thread) ----
    const int jg = jb + tj;
    const bool valid = (jg <= ig + MEM) && (jg < JTOT);
    float o2[16];
#pragma unroll
    for (int q = 0; q < 16; ++q) o2[q] = 0.f;
    if (valid) {
      const int rb = rel_bucket(ig - jg) * 16;
#pragma unroll
      for (int kc = 0; kc < 2; ++kc) {
        float sa[8];
#pragma unroll
        for (int q = 0; q < 8; ++q) sa[q] = 0.f;
#pragma unroll
        for (int h = 0; h < 16; ++h) {
          float s = S_lds[tj * JPLANE + h * 16 + ti];
          float4 pa = *(const float4*)&pre_s[h * 16 + kc * 8];
          float4 pb = *(const float4*)&pre_s[h * 16 + kc * 8 + 4];
          sa[0] += s * pa.x; sa[1] += s * pa.y; sa[2] += s * pa.z; sa[3] += s * pa.w;
          sa[4] += s * pb.x; sa[5] += s * pb.y; sa[6] += s * pb.z; sa[7] += s * pb.w;
        }
#pragma unroll
        for (int kk = 0; kk < 8; ++kk) {
          const int k = kc * 8 + kk;
          const float p = __expf(sa[kk] + relt[rb + k] - Ml[k * 16 + ti]) * iLl[k * 16 + ti];
#pragma unroll
          for (int kq = 0; kq < 4; ++kq) {
            float4 po = *(const float4*)&post_s[k * 16 + kq * 4];
            o2[kq * 4 + 0] += p * po.x;
            o2[kq * 4 + 1] += p * po.y;
            o2[kq * 4 + 2] += p * po.z;
            o2[kq * 4 + 3] += p * po.w;
          }
        }
      }
    }
#pragma unroll
    for (int k2 = 0; k2 < 16; ++k2)
      P_lds[(k2 * 16 + ti) * 40 + tj] = (_Float16)o2[k2];
    __syncthreads();
    // ---- PV MFMA ----
#pragma unroll
    for (int n = 0; n < 2; ++n) {
      const int h = w * 2 + n;
      half8 af = *(const half8*)&P_lds[((h * 16) + (lane & 15)) * 40 + (lane >> 4) * 8];
#pragma unroll
      for (int T = 0; T < 4; ++T) {
        const _Float16* vb = vT + ((size_t)h * DH + 16 * T + (lane & 15)) * JP + jb + (lane >> 4) * 8;
        oacc[n][T] = __builtin_amdgcn_mfma_f32_16x16x32_f16(af, *(const half8*)vb, oacc[n][T], 0, 0, 0);
      }
    }
    // no loop-end barrier: S_lds(n+1) writes are fenced by the post-QK
    // barrier before any P_lds(n+1) write; P_lds reads complete before it.
  }
  // ---- atomic accumulate into ctx ----
#pragma unroll
  for (int n = 0; n < 2; ++n) {
    const int h = w * 2 + n;
#pragma unroll
    for (int T = 0; T < 4; ++T)
#pragma unroll
      for (int r = 0; r < 4; ++r) {
        const int row = i0 + (lane >> 4) * 4 + r;
        const int col = h * DH + 16 * T + (lane & 15);
        atomicAdd(&ctx[(size_t)row * DIMN + col], oacc[n][T][r]);
      }
  }
}

// ---------------------------------------------------------------------------
extern "C" void kernel_launch(void* const* d_in, const int* in_sizes, int n_in,
                              void* d_out, int out_size, void* d_ws, size_t ws_size,
                              hipStream_t stream)
{
  const float* x         = (const float*)d_in[0];
  const float* rot       = (const float*)d_in[1];
  const float* Wq        = (const float*)d_in[2];
  const float* Wk        = (const float*)d_in[3];
  const float* Wv        = (const float*)d_in[4];
  const float* Wo        = (const float*)d_in[5];
  const float* bo        = (const float*)d_in[6];
  const float* mem_k     = (const float*)d_in[7];
  const float* mem_v     = (const float*)d_in[8];
  const float* pre_proj  = (const float*)d_in[9];
  const float* post_proj = (const float*)d_in[10];
  const float* qk_scale  = (const float*)d_in[11];
  const float* rel_table = (const float*)d_in[12];
  float* out = (float*)d_out;
  float* ws  = (float*)d_ws;

  // ---- workspace layout (~58 MB) ----
  float* tmp    = ws;                              // 3*N*DIM = 6,291,456 f
  float* ctx    = ws;                              // aliases tmp (tmp dead first)
  float* mpart  = ws + 6291456;                    // 11*16*2048 = 360,448
  float* lpart  = mpart + 360448;
  float* Mf     = lpart + 360448;                  // 32,768
  float* Lf     = Mf + 32768;
  _Float16* xh  = (_Float16*)(Lf + 32768);         // 2,097,152 h
  _Float16* WqT = xh + 2097152;                    // 1,048,576 h each
  _Float16* WkT = WqT + 1048576;
  _Float16* WvT = WkT + 1048576;
  _Float16* WoT = WvT + 1048576;
  _Float16* qh  = WoT + 1048576;                   // 2,097,152 h
  _Float16* kh  = qh + 2097152;                    // 2,162,688 h
  _Float16* vT  = kh + 2162688;                    // 2,162,688 h
  _Float16* vh  = vT + 2162688;                    // 2,162,688 h
  _Float16* ctxh = xh;   // alias: xh dead after QKV GEMMs
  (void)in_sizes; (void)n_in; (void)out_size; (void)ws_size;

  // ---- fp16 conversions ----
  convert_f16<<<2048, 256, 0, stream>>>(x, xh, N_SEQ * DIMN / 4);
  convtrans<<<dim3(16, 16), 256, 0, stream>>>(Wq, WqT, DIMN, DIMN);
  convtrans<<<dim3(16, 16), 256, 0, stream>>>(Wk, WkT, DIMN, DIMN);
  convtrans<<<dim3(16, 16), 256, 0, stream>>>(Wv, WvT, DIMN, DIMN);
  convtrans<<<dim3(16, 16), 256, 0, stream>>>(Wo, WoT, DIMN, DIMN);

  // ---- QKV projections (fp16 MFMA) ----
  dim3 gB(DIMN / 64, N_SEQ / 64);
  gemm_f16<<<gB, 256, 0, stream>>>(xh, WqT, tmp, nullptr, N_SEQ, DIMN, DIMN);
  gemm_f16<<<gB, 256, 0, stream>>>(xh, WkT, tmp + (size_t)N_SEQ * DIMN, nullptr, N_SEQ, DIMN, DIMN);
  gemm_f16<<<gB, 256, 0, stream>>>(xh, WvT, tmp + 2 * (size_t)N_SEQ * DIMN, nullptr, N_SEQ, DIMN, DIMN);

  {
    const int waves = NH * N_SEQ + NH * MEM + NH * (JP - JTOT);
    postproc<<<waves / 4, 256, 0, stream>>>(tmp, rot, mem_k, mem_v, qk_scale, qh, kh, vh);
  }
  transpose_v<<<dim3(JP / 64, NH), 256, 0, stream>>>(vh, vT);

  // ctx zero-init (tmp is dead now); pass2 accumulates atomically
  hipMemsetAsync(ctx, 0, (size_t)N_SEQ * DIMN * sizeof(float), stream);

  attn_pass1<<<dim3(N_SEQ / 16, C_SPLIT), 512, 0, stream>>>(
      qh, kh, pre_proj, rel_table, mpart, lpart);
  merge_ml<<<NH * N_SEQ / 256, 256, 0, stream>>>(mpart, lpart, Mf, Lf);
  attn_pass2<<<dim3(N_SEQ / 16, C_SPLIT), 512, 0, stream>>>(
      qh, kh, vT, pre_proj, post_proj, rel_table, Mf, Lf, ctx);

  convert_f16<<<2048, 256, 0, stream>>>(ctx, ctxh, N_SEQ * DIMN / 4);
  gemm_f16<<<gB, 256, 0, stream>>>(ctxh, WoT, out, bo, N_SEQ, DIMN, DIMN);
}

// Round 9
// 476.472 us; speedup vs baseline: 1.3554x; 1.3554x over previous
//
#include <hip/hip_runtime.h>
#include <math.h>
#include <float.h>

// Problem constants
#define N_SEQ 2048
#define DIMN  1024
#define NH    16
#define DH    64
#define ROT   32
#define MEM   16
#define JTOT  (N_SEQ + MEM)   // 2064
#define JP    2112            // padded to x32 (pad keys zeroed, masked)
#define NB    32
#define REL_SCALE 8.0f
#define C_SPLIT 6
#define JSP   352             // 11 tiles of 32; 6*352 = 2112 = JP
#define SST   20              // S16 col stride (halves): b64-aligned, ~2-way banks

typedef __attribute__((ext_vector_type(8))) _Float16 half8;
typedef __attribute__((ext_vector_type(4))) _Float16 half4;
typedef __attribute__((ext_vector_type(4))) float floatx4;

// ---------------------------------------------------------------------------
// f32 -> f16 elementwise (vectorized)
// ---------------------------------------------------------------------------
__global__ __launch_bounds__(256) void convert_f16(
    const float* __restrict__ in, _Float16* __restrict__ out, int n4)
{
  const int t = blockIdx.x * 256 + threadIdx.x;
  if (t >= n4) return;
  float4 v = ((const float4*)in)[t];
  half4 o = { (_Float16)v.x, (_Float16)v.y, (_Float16)v.z, (_Float16)v.w };
  *(half4*)&out[(size_t)t * 4] = o;
}

// ---------------------------------------------------------------------------
// W [K][N] f32 -> WT [N][K] f16 (64x64 LDS tiles)
// ---------------------------------------------------------------------------
__global__ __launch_bounds__(256) void convtrans(
    const float* __restrict__ W, _Float16* __restrict__ WT, int K, int N)
{
  __shared__ _Float16 tile[64][72];
  const int k0 = blockIdx.y * 64, n0 = blockIdx.x * 64;
  const int t = threadIdx.x;
#pragma unroll
  for (int p = 0; p < 4; ++p) {
    const int r = (t >> 4) + 16 * p;
    const int c = (t & 15) * 4;
    float4 wv = *(const float4*)&W[(size_t)(k0 + r) * N + n0 + c];
    tile[r][c + 0] = (_Float16)wv.x;
    tile[r][c + 1] = (_Float16)wv.y;
    tile[r][c + 2] = (_Float16)wv.z;
    tile[r][c + 3] = (_Float16)wv.w;
  }
  __syncthreads();
#pragma unroll
  for (int p = 0; p < 2; ++p) {
    const int n = (t >> 3) + 32 * p;
    const int kc = (t & 7) * 8;
    half8 o;
#pragma unroll
    for (int j = 0; j < 8; ++j) o[j] = tile[kc + j][n];
    *(half8*)&WT[(size_t)(n0 + n) * K + k0 + kc] = o;
  }
}

// ---------------------------------------------------------------------------
// fp16 MFMA GEMM: C(f32) = A(f16,[M][K]) @ BT(f16,[N][K])^T (+bias)
// ---------------------------------------------------------------------------
__global__ __launch_bounds__(256) void gemm_f16(
    const _Float16* __restrict__ A, const _Float16* __restrict__ BT,
    float* __restrict__ C, const float* __restrict__ bias,
    int M, int K, int N)
{
  const int tid = threadIdx.x;
  const int w = tid >> 6, lane = tid & 63;
  const int m0 = blockIdx.y * 64 + w * 16;
  const int n0 = blockIdx.x * 64;
  const int lr = lane & 15, lk = (lane >> 4) * 8;
  const _Float16* Ap = A + (size_t)(m0 + lr) * K + lk;
  const _Float16* Bp = BT + (size_t)(n0 + lr) * K + lk;
  floatx4 acc[4];
#pragma unroll
  for (int T = 0; T < 4; ++T) acc[T] = (floatx4){0.f, 0.f, 0.f, 0.f};
#pragma unroll 2
  for (int k0 = 0; k0 < K; k0 += 32) {
    half8 af = *(const half8*)(Ap + k0);
#pragma unroll
    for (int T = 0; T < 4; ++T) {
      half8 bf = *(const half8*)(Bp + (size_t)T * 16 * K + k0);
      acc[T] = __builtin_amdgcn_mfma_f32_16x16x32_f16(af, bf, acc[T], 0, 0, 0);
    }
  }
#pragma unroll
  for (int T = 0; T < 4; ++T) {
    const int col = n0 + T * 16 + lr;
    const float bb = bias ? bias[col] : 0.f;
#pragma unroll
    for (int r = 0; r < 4; ++r) {
      const int row = m0 + (lane >> 4) * 4 + r;
      C[(size_t)row * N + col] = acc[T][r] + bb;
    }
  }
}

// ---------------------------------------------------------------------------
// Rotary + l2norm + fp16 layout. qh scaled by 1/clip(exp(qk_scale),0.01).
// ---------------------------------------------------------------------------
__global__ __launch_bounds__(256) void postproc(
    const float* __restrict__ tmp, const float* __restrict__ rot,
    const float* __restrict__ mem_k, const float* __restrict__ mem_v,
    const float* __restrict__ qk_scale,
    _Float16* __restrict__ qh, _Float16* __restrict__ kh, _Float16* __restrict__ vh)
{
  const int gw = (blockIdx.x * 256 + threadIdx.x) >> 6;
  const int lane = threadIdx.x & 63;
  const int TQ = NH * N_SEQ;
  const int TM = TQ + NH * MEM;
  const int TP = TM + NH * (JP - JTOT);
  if (gw < TQ) {
    const int h = gw >> 11;
    const int i = gw & (N_SEQ - 1);
    const size_t base = (size_t)i * DIMN + h * DH + lane;
    float q = tmp[base];
    float k = tmp[base + (size_t)N_SEQ * DIMN];
    float v = tmp[base + 2 * (size_t)N_SEQ * DIMN];
    float cf = 1.f, sf = 0.f;
    if (lane < ROT) { float f = rot[(size_t)i * ROT + lane]; cf = cosf(f); sf = sinf(f); }
    float qp = __shfl_xor(q, 16);
    float kp = __shfl_xor(k, 16);
    float vp = __shfl_xor(v, 16);
    if (lane < ROT) {
      float sgn = (lane < 16) ? -1.f : 1.f;
      q = q * cf + sgn * qp * sf;
      k = k * cf + sgn * kp * sf;
      v = v * cf + sgn * vp * sf;
    }
    float nq = q * q, nk = k * k;
#pragma unroll
    for (int off = 32; off; off >>= 1) { nq += __shfl_xor(nq, off); nk += __shfl_xor(nk, off); }
    q *= 1.f / fmaxf(sqrtf(nq), 1e-12f);
    k *= 1.f / fmaxf(sqrtf(nk), 1e-12f);
    float scl = 1.0f / fmaxf(__expf(qk_scale[h]), 0.01f);
    qh[((size_t)h * N_SEQ + i) * DH + lane] = (_Float16)(q * scl);
    kh[((size_t)h * JP + MEM + i) * DH + lane] = (_Float16)k;
    vh[((size_t)h * JP + MEM + i) * DH + lane] = (_Float16)v;
  } else if (gw < TM) {
    const int r = gw - TQ;
    const int h = r >> 4, mm = r & 15;
    float k = mem_k[((size_t)h * MEM + mm) * DH + lane];
    float v = mem_v[((size_t)h * MEM + mm) * DH + lane];
    float nk = k * k;
#pragma unroll
    for (int off = 32; off; off >>= 1) nk += __shfl_xor(nk, off);
    k *= 1.f / fmaxf(sqrtf(nk), 1e-12f);
    kh[((size_t)h * JP + mm) * DH + lane] = (_Float16)k;
    vh[((size_t)h * JP + mm) * DH + lane] = (_Float16)v;
  } else if (gw < TP) {
    const int r = gw - TM;
    const int h = r / (JP - JTOT), jr = JTOT + r % (JP - JTOT);
    kh[((size_t)h * JP + jr) * DH + lane] = (_Float16)0.f;
    vh[((size_t)h * JP + jr) * DH + lane] = (_Float16)0.f;
  }
}

// ---------------------------------------------------------------------------
// vh[h][j][d] -> vT[h][d][j]
// ---------------------------------------------------------------------------
__global__ __launch_bounds__(256) void transpose_v(
    const _Float16* __restrict__ vh, _Float16* __restrict__ vT)
{
  __shared__ _Float16 tile[64][72];
  const int h = blockIdx.y;
  const int j0 = blockIdx.x * 64;
  const int t = threadIdx.x;
#pragma unroll
  for (int p = 0; p < 2; ++p) {
    const int jr = (t >> 3) + 32 * p;
    const int dc = (t & 7) * 8;
    half8 v = *(const half8*)(vh + ((size_t)h * JP + j0 + jr) * DH + dc);
    *(half8*)&tile[jr][dc] = v;
  }
  __syncthreads();
#pragma unroll
  for (int p = 0; p < 2; ++p) {
    const int d = (t >> 3) + 32 * p;
    const int jc = (t & 7) * 8;
    half8 o;
#pragma unroll
    for (int r = 0; r < 8; ++r) o[r] = tile[jc + r][d];
    *(half8*)(vT + ((size_t)h * DH + d) * JP + j0 + jc) = o;
  }
}

__device__ __forceinline__ int rel_bucket(int n) {
  if (n < 0) n = 0;
  if (n < 16) return n;
  int v = 16 + (int)(logf((float)n * 0.0625f) * 7.6944042f);
  return v > 31 ? 31 : v;
}

// ---------------------------------------------------------------------------
// Pass 1 (512 thr, 8 waves x 2 heads): QK MFMA -> S16(f16, B-frag layout)
// -> premix via 16x16x16 MFMA (pre^T in regs) -> register online (m,l)
// -> shfl j-reduce -> mpart. Mix is MFMA+exp only (issue-bound fix, R8).
// S16 layout: [col = i*32+j][h], col stride SST=20 halves.
// ---------------------------------------------------------------------------
__global__ __launch_bounds__(512, 2) void attn_pass1(
    const _Float16* __restrict__ qh, const _Float16* __restrict__ kh,
    const float* __restrict__ pre_proj, const float* __restrict__ rel_table,
    float* __restrict__ mpart, float* __restrict__ lpart)
{
  const int i0 = blockIdx.x * 16;
  const int c = blockIdx.y;
  const int jlo = c * JSP;
  if (jlo >= i0 + 32) return;
  const int jhi = min(min(jlo + JSP, JP), (i0 + 63) & ~31);
  const int tid = threadIdx.x;
  const int lane = tid & 63, w = tid >> 6;
  const int n15 = lane & 15, q4 = lane >> 4;

  __shared__ _Float16 S16[512 * SST];   // 20,480 B
  __shared__ float relt_f[NB * NH];     // 2,048 B

  relt_f[tid] = rel_table[tid] * REL_SCALE;

  // pre^T A-fragment (A[m=k][kdim=h]): lane (q4,n15) holds pre[h=q4*4+t][k=n15]
  half4 preA;
#pragma unroll
  for (int t = 0; t < 4; ++t) preA[t] = (_Float16)pre_proj[(q4 * 4 + t) * 16 + n15];

  half8 qf[2][2];
#pragma unroll
  for (int n = 0; n < 2; ++n) {
    const int h = w * 2 + n;
    const _Float16* qb = qh + ((size_t)h * N_SEQ + i0 + n15) * DH + q4 * 8;
    qf[n][0] = *(const half8*)qb;
    qf[n][1] = *(const half8*)(qb + 32);
  }
  float m2[2][4], l2[2][4];
#pragma unroll
  for (int p = 0; p < 2; ++p)
#pragma unroll
    for (int r = 0; r < 4; ++r) { m2[p][r] = -1e30f; l2[p][r] = 0.f; }
  __syncthreads();

  for (int jb = jlo; jb < jhi; jb += 32) {
    // ---- QK MFMA -> S16 (f16) ----
#pragma unroll
    for (int n = 0; n < 2; ++n) {
      const int h = w * 2 + n;
#pragma unroll
      for (int T = 0; T < 2; ++T) {
        floatx4 acc = {0.f, 0.f, 0.f, 0.f};
        const _Float16* kb = kh + ((size_t)h * JP + jb + 16 * T + n15) * DH + q4 * 8;
        acc = __builtin_amdgcn_mfma_f32_16x16x32_f16(qf[n][0], *(const half8*)kb, acc, 0, 0, 0);
        acc = __builtin_amdgcn_mfma_f32_16x16x32_f16(qf[n][1], *(const half8*)(kb + 32), acc, 0, 0, 0);
        const int jcol = n15 + 16 * T;
#pragma unroll
        for (int r = 0; r < 4; ++r) {
          const int i = q4 * 4 + r;
          S16[(i * 32 + jcol) * SST + h] = (_Float16)acc[r];
        }
      }
    }
    __syncthreads();
    // ---- premix MFMA + online (m,l) ----
#pragma unroll
    for (int mm = 0; mm < 4; ++mm) {
      const int mc = w * 4 + mm;
      const int par = mm >> 1;
      const int i = 2 * w + par;
      const int col = mc * 16 + n15;
      half4 bf = *(const half4*)&S16[col * SST + q4 * 4];
      floatx4 sp = __builtin_amdgcn_mfma_f32_16x16x16f16(preA, bf, (floatx4){0.f, 0.f, 0.f, 0.f}, 0, 0, 0);
      const int ig = i0 + i;
      const int jg = jb + n15 + (mc & 1) * 16;
      const bool valid = (jg <= ig + MEM) && (jg < JTOT);
      if (valid) {
        const int rb = rel_bucket(ig - jg);
        float4 rr = *(const float4*)&relt_f[rb * 16 + q4 * 4];
        const float rv[4] = { rr.x, rr.y, rr.z, rr.w };
#pragma unroll
        for (int r = 0; r < 4; ++r) {
          const float s = sp[r] + rv[r];
          const float mo = m2[par][r];
          const float mn = fmaxf(mo, s);
          const float e = __expf(fminf(mo, s) - mn);
          l2[par][r] = (s > mo) ? (l2[par][r] * e + 1.0f) : (l2[par][r] + e);
          m2[par][r] = mn;
        }
      }
    }
    __syncthreads();
  }
  // ---- shfl j-reduce over the 16 lanes of each quad ----
#pragma unroll
  for (int off = 1; off < 16; off <<= 1) {
#pragma unroll
    for (int p = 0; p < 2; ++p)
#pragma unroll
      for (int r = 0; r < 4; ++r) {
        float mo = __shfl_xor(m2[p][r], off);
        float lo = __shfl_xor(l2[p][r], off);
        float mn = fmaxf(m2[p][r], mo);
        l2[p][r] = l2[p][r] * __expf(m2[p][r] - mn) + lo * __expf(mo - mn);
        m2[p][r] = mn;
      }
  }
  if (n15 == 0) {
#pragma unroll
    for (int p = 0; p < 2; ++p) {
      const int ig = i0 + 2 * w + p;
#pragma unroll
      for (int r = 0; r < 4; ++r) {
        const int k = q4 * 4 + r;
        mpart[((size_t)c * NH + k) * N_SEQ + ig] = m2[p][r];
        lpart[((size_t)c * NH + k) * N_SEQ + ig] = l2[p][r];
      }
    }
  }
}

// ---------------------------------------------------------------------------
__global__ __launch_bounds__(256) void merge_ml(
    const float* __restrict__ mpart, const float* __restrict__ lpart,
    float* __restrict__ Mf, float* __restrict__ Lf)
{
  const int t = blockIdx.x * 256 + threadIdx.x;
  const int i = t & (N_SEQ - 1);
  const int lim = (i & ~15) + 32;
  const int h = t >> 11;
  float m = -1e30f;
#pragma unroll
  for (int c = 0; c < C_SPLIT; ++c)
    if (c * JSP < lim) m = fmaxf(m, mpart[((size_t)c * NH + h) * N_SEQ + i]);
  float l = 0.f;
#pragma unroll
  for (int c = 0; c < C_SPLIT; ++c)
    if (c * JSP < lim) {
      float mc = mpart[((size_t)c * NH + h) * N_SEQ + i];
      l += lpart[((size_t)c * NH + h) * N_SEQ + i] * __expf(mc - m);
    }
  Mf[t] = m;
  Lf[t] = l;
}

// ---------------------------------------------------------------------------
// Pass 2 (512 thr): QK MFMA -> S16 -> premix MFMA -> exp in regs (premix
// C-layout == postmix B-layout, same lane!) -> postmix MFMA -> P2 A-frags
// -> PV MFMA -> atomic ctx. 2 barriers/tile.
// ---------------------------------------------------------------------------
__global__ __launch_bounds__(512, 2) void attn_pass2(
    const _Float16* __restrict__ qh, const _Float16* __restrict__ kh,
    const _Float16* __restrict__ vT,
    const float* __restrict__ pre_proj, const float* __restrict__ post_proj,
    const float* __restrict__ rel_table,
    const float* __restrict__ Mf, const float* __restrict__ Lf,
    float* __restrict__ ctx)
{
  const int i0 = blockIdx.x * 16;
  const int c = blockIdx.y;
  const int jlo = c * JSP;
  if (jlo >= i0 + 32) return;
  const int jhi = min(min(jlo + JSP, JP), (i0 + 63) & ~31);
  const int tid = threadIdx.x;
  const int lane = tid & 63, w = tid >> 6;
  const int n15 = lane & 15, q4 = lane >> 4;

  __shared__ _Float16 S16[512 * SST];   // 20,480 B
  __shared__ _Float16 P2[256 * 40];     // 20,480 B
  __shared__ float relt_f[NB * NH];     // 2,048 B
  __shared__ float Ml4[256], iLl4[256]; // [i][k]

  relt_f[tid] = rel_table[tid] * REL_SCALE;
  if (tid < 256) {
    const int i = tid >> 4, k = tid & 15;
    Ml4[tid] = Mf[(size_t)k * N_SEQ + i0 + i];
    iLl4[tid] = 1.0f / Lf[(size_t)k * N_SEQ + i0 + i];
  }

  half4 preA, postA;
#pragma unroll
  for (int t = 0; t < 4; ++t) {
    preA[t] = (_Float16)pre_proj[(q4 * 4 + t) * 16 + n15];
    postA[t] = (_Float16)post_proj[(q4 * 4 + t) * 16 + n15];
  }

  half8 qf[2][2];
#pragma unroll
  for (int n = 0; n < 2; ++n) {
    const int h = w * 2 + n;
    const _Float16* qb = qh + ((size_t)h * N_SEQ + i0 + n15) * DH + q4 * 8;
    qf[n][0] = *(const half8*)qb;
    qf[n][1] = *(const half8*)(qb + 32);
  }
  floatx4 oacc[2][4];
#pragma unroll
  for (int n = 0; n < 2; ++n)
#pragma unroll
    for (int T = 0; T < 4; ++T) oacc[n][T] = (floatx4){0.f, 0.f, 0.f, 0.f};
  __syncthreads();

  for (int jb = jlo; jb < jhi; jb += 32) {
    // ---- QK MFMA -> S16 (f16) ----
#pragma unroll
    for (int n = 0; n < 2; ++n) {
      const int h = w * 2 + n;
#pragma unroll
      for (int T = 0; T < 2; ++T) {
        floatx4 acc = {0.f, 0.f, 0.f, 0.f};
        const _Float16* kb = kh + ((size_t)h * JP + jb + 16 * T + n15) * DH + q4 * 8;
        acc = __builtin_amdgcn_mfma_f32_16x16x32_f16(qf[n][0], *(const half8*)kb, acc, 0, 0, 0);
        acc = __builtin_amdgcn_mfma_f32_16x16x32_f16(qf[n][1], *(const half8*)(kb + 32), acc, 0, 0, 0);
        const int jcol = n15 + 16 * T;
#pragma unroll
        for (int r = 0; r < 4; ++r) {
          const int i = q4 * 4 + r;
          S16[(i * 32 + jcol) * SST + h] = (_Float16)acc[r];
        }
      }
    }
    __syncthreads();
    // ---- premix MFMA -> exp (regs) -> postmix MFMA -> P2 ----
#pragma unroll
    for (int mm = 0; mm < 4; ++mm) {
      const int mc = w * 4 + mm;
      const int i = 2 * w + (mm >> 1);
      const int jj = n15 + (mc & 1) * 16;
      const int col = mc * 16 + n15;
      half4 bf = *(const half4*)&S16[col * SST + q4 * 4];
      floatx4 sp = __builtin_amdgcn_mfma_f32_16x16x16f16(preA, bf, (floatx4){0.f, 0.f, 0.f, 0.f}, 0, 0, 0);
      const int ig = i0 + i;
      const int jg = jb + jj;
      const bool valid = (jg <= ig + MEM) && (jg < JTOT);
      const int rb = rel_bucket(ig - jg);
      float4 rr = *(const float4*)&relt_f[rb * 16 + q4 * 4];
      float4 Mr = *(const float4*)&Ml4[i * 16 + q4 * 4];
      float4 Lr = *(const float4*)&iLl4[i * 16 + q4 * 4];
      const float rv[4] = { rr.x, rr.y, rr.z, rr.w };
      const float Mv[4] = { Mr.x, Mr.y, Mr.z, Mr.w };
      const float Lv[4] = { Lr.x, Lr.y, Lr.z, Lr.w };
      half4 p4;
#pragma unroll
      for (int r = 0; r < 4; ++r) {
        const float p = valid ? __expf(sp[r] + rv[r] - Mv[r]) * Lv[r] : 0.f;
        p4[r] = (_Float16)p;
      }
      // postmix: premix C-layout == postmix B-layout (same lane, same regs)
      floatx4 od = __builtin_amdgcn_mfma_f32_16x16x16f16(postA, p4, (floatx4){0.f, 0.f, 0.f, 0.f}, 0, 0, 0);
#pragma unroll
      for (int r = 0; r < 4; ++r) {
        const int k2 = q4 * 4 + r;
        P2[(k2 * 16 + i) * 40 + jj] = (_Float16)od[r];
      }
    }
    __syncthreads();
    // ---- PV MFMA ----
#pragma unroll
    for (int n = 0; n < 2; ++n) {
      const int h = w * 2 + n;
      half8 af = *(const half8*)&P2[(h * 16 + n15) * 40 + q4 * 8];
#pragma unroll
      for (int T = 0; T < 4; ++T) {
        const _Float16* vb = vT + ((size_t)h * DH + 16 * T + n15) * JP + jb + q4 * 8;
        oacc[n][T] = __builtin_amdgcn_mfma_f32_16x16x32_f16(af, *(const half8*)vb, oacc[n][T], 0, 0, 0);
      }
    }
    // no loop-end barrier: next-tile S16 writes are safe (all premix reads
    // precede the pre-PV barrier); next-tile P2 writes follow next post-QK
    // barrier, after this tile's PV reads.
  }
  // ---- atomic accumulate into ctx ----
#pragma unroll
  for (int n = 0; n < 2; ++n) {
    const int h = w * 2 + n;
#pragma unroll
    for (int T = 0; T < 4; ++T)
#pragma unroll
      for (int r = 0; r < 4; ++r) {
        const int row = i0 + q4 * 4 + r;
        const int col = h * DH + 16 * T + n15;
        atomicAdd(&ctx[(size_t)row * DIMN + col], oacc[n][T][r]);
      }
  }
}

// ---------------------------------------------------------------------------
extern "C" void kernel_launch(void* const* d_in, const int* in_sizes, int n_in,
                              void* d_out, int out_size, void* d_ws, size_t ws_size,
                              hipStream_t stream)
{
  const float* x         = (const float*)d_in[0];
  const float* rot       = (const float*)d_in[1];
  const float* Wq        = (const float*)d_in[2];
  const float* Wk        = (const float*)d_in[3];
  const float* Wv        = (const float*)d_in[4];
  const float* Wo        = (const float*)d_in[5];
  const float* bo        = (const float*)d_in[6];
  const float* mem_k     = (const float*)d_in[7];
  const float* mem_v     = (const float*)d_in[8];
  const float* pre_proj  = (const float*)d_in[9];
  const float* post_proj = (const float*)d_in[10];
  const float* qk_scale  = (const float*)d_in[11];
  const float* rel_table = (const float*)d_in[12];
  float* out = (float*)d_out;
  float* ws  = (float*)d_ws;

  // ---- workspace layout (~57 MB) ----
  float* tmp    = ws;                              // 3*N*DIM = 6,291,456 f
  float* ctx    = ws;                              // aliases tmp (tmp dead first)
  float* mpart  = ws + 6291456;                    // 6*16*2048 = 196,608
  float* lpart  = mpart + 196608;
  float* Mf     = lpart + 196608;                  // 32,768
  float* Lf     = Mf + 32768;
  _Float16* xh  = (_Float16*)(Lf + 32768);         // 2,097,152 h
  _Float16* WqT = xh + 2097152;                    // 1,048,576 h each
  _Float16* WkT = WqT + 1048576;
  _Float16* WvT = WkT + 1048576;
  _Float16* WoT = WvT + 1048576;
  _Float16* qh  = WoT + 1048576;                   // 2,097,152 h
  _Float16* kh  = qh + 2097152;                    // 2,162,688 h
  _Float16* vT  = kh + 2162688;                    // 2,162,688 h
  _Float16* vh  = vT + 2162688;                    // 2,162,688 h
  _Float16* ctxh = xh;   // alias: xh dead after QKV GEMMs
  (void)in_sizes; (void)n_in; (void)out_size; (void)ws_size;

  // ---- fp16 conversions ----
  convert_f16<<<2048, 256, 0, stream>>>(x, xh, N_SEQ * DIMN / 4);
  convtrans<<<dim3(16, 16), 256, 0, stream>>>(Wq, WqT, DIMN, DIMN);
  convtrans<<<dim3(16, 16), 256, 0, stream>>>(Wk, WkT, DIMN, DIMN);
  convtrans<<<dim3(16, 16), 256, 0, stream>>>(Wv, WvT, DIMN, DIMN);
  convtrans<<<dim3(16, 16), 256, 0, stream>>>(Wo, WoT, DIMN, DIMN);

  // ---- QKV projections (fp16 MFMA) ----
  dim3 gB(DIMN / 64, N_SEQ / 64);
  gemm_f16<<<gB, 256, 0, stream>>>(xh, WqT, tmp, nullptr, N_SEQ, DIMN, DIMN);
  gemm_f16<<<gB, 256, 0, stream>>>(xh, WkT, tmp + (size_t)N_SEQ * DIMN, nullptr, N_SEQ, DIMN, DIMN);
  gemm_f16<<<gB, 256, 0, stream>>>(xh, WvT, tmp + 2 * (size_t)N_SEQ * DIMN, nullptr, N_SEQ, DIMN, DIMN);

  {
    const int waves = NH * N_SEQ + NH * MEM + NH * (JP - JTOT);
    postproc<<<waves / 4, 256, 0, stream>>>(tmp, rot, mem_k, mem_v, qk_scale, qh, kh, vh);
  }
  transpose_v<<<dim3(JP / 64, NH), 256, 0, stream>>>(vh, vT);

  // ctx zero-init (tmp is dead now); pass2 accumulates atomically
  hipMemsetAsync(ctx, 0, (size_t)N_SEQ * DIMN * sizeof(float), stream);

  attn_pass1<<<dim3(N_SEQ / 16, C_SPLIT), 512, 0, stream>>>(
      qh, kh, pre_proj, rel_table, mpart, lpart);
  merge_ml<<<NH * N_SEQ / 256, 256, 0, stream>>>(mpart, lpart, Mf, Lf);
  attn_pass2<<<dim3(N_SEQ / 16, C_SPLIT), 512, 0, stream>>>(
      qh, kh, vT, pre_proj, post_proj, rel_table, Mf, Lf, ctx);

  convert_f16<<<2048, 256, 0, stream>>>(ctx, ctxh, N_SEQ * DIMN / 4);
  gemm_f16<<<gB, 256, 0, stream>>>(ctxh, WoT, out, bo, N_SEQ, DIMN, DIMN);
}

// Round 10
// 455.221 us; speedup vs baseline: 1.4187x; 1.0467x over previous
//
#include <hip/hip_runtime.h>
#include <math.h>
#include <float.h>

// Problem constants
#define N_SEQ 2048
#define DIMN  1024
#define NH    16
#define DH    64
#define ROT   32
#define MEM   16
#define JTOT  (N_SEQ + MEM)   // 2064
#define JP    2112            // padded to x32 (pad keys zeroed, masked)
#define NB    32
#define REL_SCALE 8.0f
#define C_SPLIT 6
#define JSP   352             // 11 tiles of 32; 6*352 = 2112 = JP
#define SST   20              // S16 col stride (halves); x4 halves -> b64-aligned

typedef __attribute__((ext_vector_type(8))) _Float16 half8;
typedef __attribute__((ext_vector_type(4))) _Float16 half4;
typedef __attribute__((ext_vector_type(4))) float floatx4;

// ---------------------------------------------------------------------------
// f32 -> f16 elementwise (vectorized)
// ---------------------------------------------------------------------------
__global__ __launch_bounds__(256) void convert_f16(
    const float* __restrict__ in, _Float16* __restrict__ out, int n4)
{
  const int t = blockIdx.x * 256 + threadIdx.x;
  if (t >= n4) return;
  float4 v = ((const float4*)in)[t];
  half4 o = { (_Float16)v.x, (_Float16)v.y, (_Float16)v.z, (_Float16)v.w };
  *(half4*)&out[(size_t)t * 4] = o;
}

// ---------------------------------------------------------------------------
// W [K][N] f32 -> WT [N][K] f16 (64x64 LDS tiles)
// ---------------------------------------------------------------------------
__global__ __launch_bounds__(256) void convtrans(
    const float* __restrict__ W, _Float16* __restrict__ WT, int K, int N)
{
  __shared__ _Float16 tile[64][72];
  const int k0 = blockIdx.y * 64, n0 = blockIdx.x * 64;
  const int t = threadIdx.x;
#pragma unroll
  for (int p = 0; p < 4; ++p) {
    const int r = (t >> 4) + 16 * p;
    const int c = (t & 15) * 4;
    float4 wv = *(const float4*)&W[(size_t)(k0 + r) * N + n0 + c];
    tile[r][c + 0] = (_Float16)wv.x;
    tile[r][c + 1] = (_Float16)wv.y;
    tile[r][c + 2] = (_Float16)wv.z;
    tile[r][c + 3] = (_Float16)wv.w;
  }
  __syncthreads();
#pragma unroll
  for (int p = 0; p < 2; ++p) {
    const int n = (t >> 3) + 32 * p;
    const int kc = (t & 7) * 8;
    half8 o;
#pragma unroll
    for (int j = 0; j < 8; ++j) o[j] = tile[kc + j][n];
    *(half8*)&WT[(size_t)(n0 + n) * K + k0 + kc] = o;
  }
}

// ---------------------------------------------------------------------------
// fp16 MFMA GEMM: C(f32) = A(f16,[M][K]) @ BT(f16,[N][K])^T (+bias)
// ---------------------------------------------------------------------------
__global__ __launch_bounds__(256) void gemm_f16(
    const _Float16* __restrict__ A, const _Float16* __restrict__ BT,
    float* __restrict__ C, const float* __restrict__ bias,
    int M, int K, int N)
{
  const int tid = threadIdx.x;
  const int w = tid >> 6, lane = tid & 63;
  const int m0 = blockIdx.y * 64 + w * 16;
  const int n0 = blockIdx.x * 64;
  const int lr = lane & 15, lk = (lane >> 4) * 8;
  const _Float16* Ap = A + (size_t)(m0 + lr) * K + lk;
  const _Float16* Bp = BT + (size_t)(n0 + lr) * K + lk;
  floatx4 acc[4];
#pragma unroll
  for (int T = 0; T < 4; ++T) acc[T] = (floatx4){0.f, 0.f, 0.f, 0.f};
#pragma unroll 2
  for (int k0 = 0; k0 < K; k0 += 32) {
    half8 af = *(const half8*)(Ap + k0);
#pragma unroll
    for (int T = 0; T < 4; ++T) {
      half8 bf = *(const half8*)(Bp + (size_t)T * 16 * K + k0);
      acc[T] = __builtin_amdgcn_mfma_f32_16x16x32_f16(af, bf, acc[T], 0, 0, 0);
    }
  }
#pragma unroll
  for (int T = 0; T < 4; ++T) {
    const int col = n0 + T * 16 + lr;
    const float bb = bias ? bias[col] : 0.f;
#pragma unroll
    for (int r = 0; r < 4; ++r) {
      const int row = m0 + (lane >> 4) * 4 + r;
      C[(size_t)row * N + col] = acc[T][r] + bb;
    }
  }
}

// ---------------------------------------------------------------------------
// Rotary + l2norm + fp16 layout. tmp is fused-QKV [i][3072]:
// q at col h*64+d, k at 1024+..., v at 2048+...
// ---------------------------------------------------------------------------
__global__ __launch_bounds__(256) void postproc(
    const float* __restrict__ tmp, const float* __restrict__ rot,
    const float* __restrict__ mem_k, const float* __restrict__ mem_v,
    const float* __restrict__ qk_scale,
    _Float16* __restrict__ qh, _Float16* __restrict__ kh, _Float16* __restrict__ vh)
{
  const int gw = (blockIdx.x * 256 + threadIdx.x) >> 6;
  const int lane = threadIdx.x & 63;
  const int TQ = NH * N_SEQ;
  const int TM = TQ + NH * MEM;
  const int TP = TM + NH * (JP - JTOT);
  if (gw < TQ) {
    const int h = gw >> 11;
    const int i = gw & (N_SEQ - 1);
    const size_t base = (size_t)i * 3072 + h * DH + lane;
    float q = tmp[base];
    float k = tmp[base + 1024];
    float v = tmp[base + 2048];
    float cf = 1.f, sf = 0.f;
    if (lane < ROT) { float f = rot[(size_t)i * ROT + lane]; cf = cosf(f); sf = sinf(f); }
    float qp = __shfl_xor(q, 16);
    float kp = __shfl_xor(k, 16);
    float vp = __shfl_xor(v, 16);
    if (lane < ROT) {
      float sgn = (lane < 16) ? -1.f : 1.f;
      q = q * cf + sgn * qp * sf;
      k = k * cf + sgn * kp * sf;
      v = v * cf + sgn * vp * sf;
    }
    float nq = q * q, nk = k * k;
#pragma unroll
    for (int off = 32; off; off >>= 1) { nq += __shfl_xor(nq, off); nk += __shfl_xor(nk, off); }
    q *= 1.f / fmaxf(sqrtf(nq), 1e-12f);
    k *= 1.f / fmaxf(sqrtf(nk), 1e-12f);
    float scl = 1.0f / fmaxf(__expf(qk_scale[h]), 0.01f);
    qh[((size_t)h * N_SEQ + i) * DH + lane] = (_Float16)(q * scl);
    kh[((size_t)h * JP + MEM + i) * DH + lane] = (_Float16)k;
    vh[((size_t)h * JP + MEM + i) * DH + lane] = (_Float16)v;
  } else if (gw < TM) {
    const int r = gw - TQ;
    const int h = r >> 4, mm = r & 15;
    float k = mem_k[((size_t)h * MEM + mm) * DH + lane];
    float v = mem_v[((size_t)h * MEM + mm) * DH + lane];
    float nk = k * k;
#pragma unroll
    for (int off = 32; off; off >>= 1) nk += __shfl_xor(nk, off);
    k *= 1.f / fmaxf(sqrtf(nk), 1e-12f);
    kh[((size_t)h * JP + mm) * DH + lane] = (_Float16)k;
    vh[((size_t)h * JP + mm) * DH + lane] = (_Float16)v;
  } else if (gw < TP) {
    const int r = gw - TM;
    const int h = r / (JP - JTOT), jr = JTOT + r % (JP - JTOT);
    kh[((size_t)h * JP + jr) * DH + lane] = (_Float16)0.f;
    vh[((size_t)h * JP + jr) * DH + lane] = (_Float16)0.f;
  }
}

// ---------------------------------------------------------------------------
// vh[h][j][d] -> vT[h][d][j]
// ---------------------------------------------------------------------------
__global__ __launch_bounds__(256) void transpose_v(
    const _Float16* __restrict__ vh, _Float16* __restrict__ vT)
{
  __shared__ _Float16 tile[64][72];
  const int h = blockIdx.y;
  const int j0 = blockIdx.x * 64;
  const int t = threadIdx.x;
#pragma unroll
  for (int p = 0; p < 2; ++p) {
    const int jr = (t >> 3) + 32 * p;
    const int dc = (t & 7) * 8;
    half8 v = *(const half8*)(vh + ((size_t)h * JP + j0 + jr) * DH + dc);
    *(half8*)&tile[jr][dc] = v;
  }
  __syncthreads();
#pragma unroll
  for (int p = 0; p < 2; ++p) {
    const int d = (t >> 3) + 32 * p;
    const int jc = (t & 7) * 8;
    half8 o;
#pragma unroll
    for (int r = 0; r < 8; ++r) o[r] = tile[jc + r][d];
    *(half8*)(vT + ((size_t)h * DH + d) * JP + j0 + jc) = o;
  }
}

__device__ __forceinline__ int rel_bucket(int n) {
  if (n < 0) n = 0;
  if (n < 16) return n;
  int v = 16 + (int)(logf((float)n * 0.0625f) * 7.6944042f);
  return v > 31 ? 31 : v;
}

// ---------------------------------------------------------------------------
// Pass 1 (512 thr, 8 waves x 2 heads): QK MFMA -> S16(f16, B-frag layout)
// -> premix via 16x16x16 MFMA (pre^T in regs) -> register online (m,l)
// -> shfl j-reduce -> mpart. (unchanged from R9 — LDS 22.5 KB, 7 blocks/CU)
// ---------------------------------------------------------------------------
__global__ __launch_bounds__(512, 2) void attn_pass1(
    const _Float16* __restrict__ qh, const _Float16* __restrict__ kh,
    const float* __restrict__ pre_proj, const float* __restrict__ rel_table,
    float* __restrict__ mpart, float* __restrict__ lpart)
{
  const int i0 = blockIdx.x * 16;
  const int c = blockIdx.y;
  const int jlo = c * JSP;
  if (jlo >= i0 + 32) return;
  const int jhi = min(min(jlo + JSP, JP), (i0 + 63) & ~31);
  const int tid = threadIdx.x;
  const int lane = tid & 63, w = tid >> 6;
  const int n15 = lane & 15, q4 = lane >> 4;

  __shared__ _Float16 S16[512 * SST];   // 20,480 B
  __shared__ float relt_f[NB * NH];     // 2,048 B

  relt_f[tid] = rel_table[tid] * REL_SCALE;

  half4 preA;
#pragma unroll
  for (int t = 0; t < 4; ++t) preA[t] = (_Float16)pre_proj[(q4 * 4 + t) * 16 + n15];

  half8 qf[2][2];
#pragma unroll
  for (int n = 0; n < 2; ++n) {
    const int h = w * 2 + n;
    const _Float16* qb = qh + ((size_t)h * N_SEQ + i0 + n15) * DH + q4 * 8;
    qf[n][0] = *(const half8*)qb;
    qf[n][1] = *(const half8*)(qb + 32);
  }
  float m2[2][4], l2[2][4];
#pragma unroll
  for (int p = 0; p < 2; ++p)
#pragma unroll
    for (int r = 0; r < 4; ++r) { m2[p][r] = -1e30f; l2[p][r] = 0.f; }
  __syncthreads();

  for (int jb = jlo; jb < jhi; jb += 32) {
#pragma unroll
    for (int n = 0; n < 2; ++n) {
      const int h = w * 2 + n;
#pragma unroll
      for (int T = 0; T < 2; ++T) {
        floatx4 acc = {0.f, 0.f, 0.f, 0.f};
        const _Float16* kb = kh + ((size_t)h * JP + jb + 16 * T + n15) * DH + q4 * 8;
        acc = __builtin_amdgcn_mfma_f32_16x16x32_f16(qf[n][0], *(const half8*)kb, acc, 0, 0, 0);
        acc = __builtin_amdgcn_mfma_f32_16x16x32_f16(qf[n][1], *(const half8*)(kb + 32), acc, 0, 0, 0);
        const int jcol = n15 + 16 * T;
#pragma unroll
        for (int r = 0; r < 4; ++r) {
          const int i = q4 * 4 + r;
          S16[(i * 32 + jcol) * SST + h] = (_Float16)acc[r];
        }
      }
    }
    __syncthreads();
#pragma unroll
    for (int mm = 0; mm < 4; ++mm) {
      const int mc = w * 4 + mm;
      const int par = mm >> 1;
      const int i = 2 * w + par;
      const int col = mc * 16 + n15;
      half4 bf = *(const half4*)&S16[col * SST + q4 * 4];
      floatx4 sp = __builtin_amdgcn_mfma_f32_16x16x16f16(preA, bf, (floatx4){0.f, 0.f, 0.f, 0.f}, 0, 0, 0);
      const int ig = i0 + i;
      const int jg = jb + n15 + (mc & 1) * 16;
      const bool valid = (jg <= ig + MEM) && (jg < JTOT);
      if (valid) {
        const int rb = rel_bucket(ig - jg);
        float4 rr = *(const float4*)&relt_f[rb * 16 + q4 * 4];
        const float rv[4] = { rr.x, rr.y, rr.z, rr.w };
#pragma unroll
        for (int r = 0; r < 4; ++r) {
          const float s = sp[r] + rv[r];
          const float mo = m2[par][r];
          const float mn = fmaxf(mo, s);
          const float e = __expf(fminf(mo, s) - mn);
          l2[par][r] = (s > mo) ? (l2[par][r] * e + 1.0f) : (l2[par][r] + e);
          m2[par][r] = mn;
        }
      }
    }
    __syncthreads();
  }
#pragma unroll
  for (int off = 1; off < 16; off <<= 1) {
#pragma unroll
    for (int p = 0; p < 2; ++p)
#pragma unroll
      for (int r = 0; r < 4; ++r) {
        float mo = __shfl_xor(m2[p][r], off);
        float lo = __shfl_xor(l2[p][r], off);
        float mn = fmaxf(m2[p][r], mo);
        l2[p][r] = l2[p][r] * __expf(m2[p][r] - mn) + lo * __expf(mo - mn);
        m2[p][r] = mn;
      }
  }
  if (n15 == 0) {
#pragma unroll
    for (int p = 0; p < 2; ++p) {
      const int ig = i0 + 2 * w + p;
#pragma unroll
      for (int r = 0; r < 4; ++r) {
        const int k = q4 * 4 + r;
        mpart[((size_t)c * NH + k) * N_SEQ + ig] = m2[p][r];
        lpart[((size_t)c * NH + k) * N_SEQ + ig] = l2[p][r];
      }
    }
  }
}

// ---------------------------------------------------------------------------
__global__ __launch_bounds__(256) void merge_ml(
    const float* __restrict__ mpart, const float* __restrict__ lpart,
    float* __restrict__ Mf, float* __restrict__ Lf)
{
  const int t = blockIdx.x * 256 + threadIdx.x;
  const int i = t & (N_SEQ - 1);
  const int lim = (i & ~15) + 32;
  const int h = t >> 11;
  float m = -1e30f;
#pragma unroll
  for (int c = 0; c < C_SPLIT; ++c)
    if (c * JSP < lim) m = fmaxf(m, mpart[((size_t)c * NH + h) * N_SEQ + i]);
  float l = 0.f;
#pragma unroll
  for (int c = 0; c < C_SPLIT; ++c)
    if (c * JSP < lim) {
      float mc = mpart[((size_t)c * NH + h) * N_SEQ + i];
      l += lpart[((size_t)c * NH + h) * N_SEQ + i] * __expf(mc - m);
    }
  Mf[t] = m;
  Lf[t] = l;
}

// ---------------------------------------------------------------------------
// Pass 2 (512 thr): QK MFMA -> S16 -> premix MFMA -> exp in regs -> postmix
// MFMA -> P2 A-frags -> PV MFMA -> atomic ctx.
// LDS = S16 (20,480) + P2 (20,480) = 40,960 B exactly -> 4 blocks/CU.
// relt / Ml / iLl live in P2's pad holes (cols 32..39 of each 40-wide row,
// never touched by mix writes; stride 80 B -> float4-aligned).
// ---------------------------------------------------------------------------
__global__ __launch_bounds__(512, 2) void attn_pass2(
    const _Float16* __restrict__ qh, const _Float16* __restrict__ kh,
    const _Float16* __restrict__ vT,
    const float* __restrict__ pre_proj, const float* __restrict__ post_proj,
    const float* __restrict__ rel_table,
    const float* __restrict__ Mf, const float* __restrict__ Lf,
    float* __restrict__ ctx)
{
  const int i0 = blockIdx.x * 16;
  const int c = blockIdx.y;
  const int jlo = c * JSP;
  if (jlo >= i0 + 32) return;
  const int jhi = min(min(jlo + JSP, JP), (i0 + 63) & ~31);
  const int tid = threadIdx.x;
  const int lane = tid & 63, w = tid >> 6;
  const int n15 = lane & 15, q4 = lane >> 4;

  __shared__ _Float16 S16[512 * SST];   // 20,480 B
  __shared__ _Float16 P2[256 * 40];     // 20,480 B (cols 32..39 = const holes)

  // hole accessor: float slot s (0..3) of row rr
#define HOLE(rr) ((float*)&P2[(rr) * 40 + 32])
  // init holes: Ml rows 0..63, iLl rows 64..127, relt rows 128..255
  if (tid < 256) {
    const int i = tid >> 4, k = tid & 15;
    HOLE(tid >> 2)[tid & 3] = Mf[(size_t)k * N_SEQ + i0 + i];
    HOLE((tid >> 2) + 64)[tid & 3] = 1.0f / Lf[(size_t)k * N_SEQ + i0 + i];
  }
  HOLE((tid >> 2) + 128)[tid & 3] = rel_table[tid] * REL_SCALE;

  half4 preA, postA;
#pragma unroll
  for (int t = 0; t < 4; ++t) {
    preA[t] = (_Float16)pre_proj[(q4 * 4 + t) * 16 + n15];
    postA[t] = (_Float16)post_proj[(q4 * 4 + t) * 16 + n15];
  }

  half8 qf[2][2];
#pragma unroll
  for (int n = 0; n < 2; ++n) {
    const int h = w * 2 + n;
    const _Float16* qb = qh + ((size_t)h * N_SEQ + i0 + n15) * DH + q4 * 8;
    qf[n][0] = *(const half8*)qb;
    qf[n][1] = *(const half8*)(qb + 32);
  }
  floatx4 oacc[2][4];
#pragma unroll
  for (int n = 0; n < 2; ++n)
#pragma unroll
    for (int T = 0; T < 4; ++T) oacc[n][T] = (floatx4){0.f, 0.f, 0.f, 0.f};
  __syncthreads();

  for (int jb = jlo; jb < jhi; jb += 32) {
    // ---- QK MFMA -> S16 (f16) ----
#pragma unroll
    for (int n = 0; n < 2; ++n) {
      const int h = w * 2 + n;
#pragma unroll
      for (int T = 0; T < 2; ++T) {
        floatx4 acc = {0.f, 0.f, 0.f, 0.f};
        const _Float16* kb = kh + ((size_t)h * JP + jb + 16 * T + n15) * DH + q4 * 8;
        acc = __builtin_amdgcn_mfma_f32_16x16x32_f16(qf[n][0], *(const half8*)kb, acc, 0, 0, 0);
        acc = __builtin_amdgcn_mfma_f32_16x16x32_f16(qf[n][1], *(const half8*)(kb + 32), acc, 0, 0, 0);
        const int jcol = n15 + 16 * T;
#pragma unroll
        for (int r = 0; r < 4; ++r) {
          const int i = q4 * 4 + r;
          S16[(i * 32 + jcol) * SST + h] = (_Float16)acc[r];
        }
      }
    }
    __syncthreads();
    // ---- premix MFMA -> exp (regs) -> postmix MFMA -> P2 ----
#pragma unroll
    for (int mm = 0; mm < 4; ++mm) {
      const int mc = w * 4 + mm;
      const int i = 2 * w + (mm >> 1);
      const int jj = n15 + (mc & 1) * 16;
      const int col = mc * 16 + n15;
      half4 bf = *(const half4*)&S16[col * SST + q4 * 4];
      floatx4 sp = __builtin_amdgcn_mfma_f32_16x16x16f16(preA, bf, (floatx4){0.f, 0.f, 0.f, 0.f}, 0, 0, 0);
      const int ig = i0 + i;
      const int jg = jb + jj;
      const bool valid = (jg <= ig + MEM) && (jg < JTOT);
      const int rb = rel_bucket(ig - jg);
      float4 rr = *(const float4*)HOLE(128 + rb * 4 + q4);
      float4 Mr = *(const float4*)HOLE(i * 4 + q4);
      float4 Lr = *(const float4*)HOLE(64 + i * 4 + q4);
      const float rv[4] = { rr.x, rr.y, rr.z, rr.w };
      const float Mv[4] = { Mr.x, Mr.y, Mr.z, Mr.w };
      const float Lv[4] = { Lr.x, Lr.y, Lr.z, Lr.w };
      half4 p4;
#pragma unroll
      for (int r = 0; r < 4; ++r) {
        const float p = valid ? __expf(sp[r] + rv[r] - Mv[r]) * Lv[r] : 0.f;
        p4[r] = (_Float16)p;
      }
      floatx4 od = __builtin_amdgcn_mfma_f32_16x16x16f16(postA, p4, (floatx4){0.f, 0.f, 0.f, 0.f}, 0, 0, 0);
#pragma unroll
      for (int r = 0; r < 4; ++r) {
        const int k2 = q4 * 4 + r;
        P2[(k2 * 16 + i) * 40 + jj] = (_Float16)od[r];
      }
    }
    __syncthreads();
    // ---- PV MFMA ----
#pragma unroll
    for (int n = 0; n < 2; ++n) {
      const int h = w * 2 + n;
      half8 af = *(const half8*)&P2[(h * 16 + n15) * 40 + q4 * 8];
#pragma unroll
      for (int T = 0; T < 4; ++T) {
        const _Float16* vb = vT + ((size_t)h * DH + 16 * T + n15) * JP + jb + q4 * 8;
        oacc[n][T] = __builtin_amdgcn_mfma_f32_16x16x32_f16(af, *(const half8*)vb, oacc[n][T], 0, 0, 0);
      }
    }
  }
#undef HOLE
  // ---- atomic accumulate into ctx ----
#pragma unroll
  for (int n = 0; n < 2; ++n) {
    const int h = w * 2 + n;
#pragma unroll
    for (int T = 0; T < 4; ++T)
#pragma unroll
      for (int r = 0; r < 4; ++r) {
        const int row = i0 + q4 * 4 + r;
        const int col = h * DH + 16 * T + n15;
        atomicAdd(&ctx[(size_t)row * DIMN + col], oacc[n][T][r]);
      }
  }
}

// ---------------------------------------------------------------------------
extern "C" void kernel_launch(void* const* d_in, const int* in_sizes, int n_in,
                              void* d_out, int out_size, void* d_ws, size_t ws_size,
                              hipStream_t stream)
{
  const float* x         = (const float*)d_in[0];
  const float* rot       = (const float*)d_in[1];
  const float* Wq        = (const float*)d_in[2];
  const float* Wk        = (const float*)d_in[3];
  const float* Wv        = (const float*)d_in[4];
  const float* Wo        = (const float*)d_in[5];
  const float* bo        = (const float*)d_in[6];
  const float* mem_k     = (const float*)d_in[7];
  const float* mem_v     = (const float*)d_in[8];
  const float* pre_proj  = (const float*)d_in[9];
  const float* post_proj = (const float*)d_in[10];
  const float* qk_scale  = (const float*)d_in[11];
  const float* rel_table = (const float*)d_in[12];
  float* out = (float*)d_out;
  float* ws  = (float*)d_ws;

  // ---- workspace layout (~57 MB) ----
  float* tmp    = ws;                              // 2048*3072 = 6,291,456 f
  float* ctx    = ws;                              // aliases tmp (tmp dead first)
  float* mpart  = ws + 6291456;                    // 6*16*2048 = 196,608
  float* lpart  = mpart + 196608;
  float* Mf     = lpart + 196608;                  // 32,768
  float* Lf     = Mf + 32768;
  _Float16* xh  = (_Float16*)(Lf + 32768);         // 2,097,152 h
  _Float16* WqT = xh + 2097152;                    // 3 x 1,048,576 h contiguous
  _Float16* WkT = WqT + 1048576;
  _Float16* WvT = WkT + 1048576;
  _Float16* WoT = WvT + 1048576;
  _Float16* qh  = WoT + 1048576;                   // 2,097,152 h
  _Float16* kh  = qh + 2097152;                    // 2,162,688 h
  _Float16* vT  = kh + 2162688;                    // 2,162,688 h
  _Float16* vh  = vT + 2162688;                    // 2,162,688 h
  _Float16* ctxh = xh;   // alias: xh dead after QKV GEMM
  (void)in_sizes; (void)n_in; (void)out_size; (void)ws_size;

  // ---- fp16 conversions ----
  convert_f16<<<2048, 256, 0, stream>>>(x, xh, N_SEQ * DIMN / 4);
  convtrans<<<dim3(16, 16), 256, 0, stream>>>(Wq, WqT, DIMN, DIMN);
  convtrans<<<dim3(16, 16), 256, 0, stream>>>(Wk, WkT, DIMN, DIMN);
  convtrans<<<dim3(16, 16), 256, 0, stream>>>(Wv, WvT, DIMN, DIMN);
  convtrans<<<dim3(16, 16), 256, 0, stream>>>(Wo, WoT, DIMN, DIMN);

  // ---- fused QKV projection: BT = [WqT;WkT;WvT] (3072 x 1024), one launch ----
  gemm_f16<<<dim3(3072 / 64, N_SEQ / 64), 256, 0, stream>>>(
      xh, WqT, tmp, nullptr, N_SEQ, DIMN, 3072);

  {
    const int waves = NH * N_SEQ + NH * MEM + NH * (JP - JTOT);
    postproc<<<waves / 4, 256, 0, stream>>>(tmp, rot, mem_k, mem_v, qk_scale, qh, kh, vh);
  }
  transpose_v<<<dim3(JP / 64, NH), 256, 0, stream>>>(vh, vT);

  // ctx zero-init (tmp is dead now); pass2 accumulates atomically
  hipMemsetAsync(ctx, 0, (size_t)N_SEQ * DIMN * sizeof(float), stream);

  attn_pass1<<<dim3(N_SEQ / 16, C_SPLIT), 512, 0, stream>>>(
      qh, kh, pre_proj, rel_table, mpart, lpart);
  merge_ml<<<NH * N_SEQ / 256, 256, 0, stream>>>(mpart, lpart, Mf, Lf);
  attn_pass2<<<dim3(N_SEQ / 16, C_SPLIT), 512, 0, stream>>>(
      qh, kh, vT, pre_proj, post_proj, rel_table, Mf, Lf, ctx);

  convert_f16<<<2048, 256, 0, stream>>>(ctx, ctxh, N_SEQ * DIMN / 4);
  gemm_f16<<<dim3(DIMN / 64, N_SEQ / 64), 256, 0, stream>>>(
      ctxh, WoT, out, bo, N_SEQ, DIMN, DIMN);
}